// Round 4
// baseline (671.304 us; speedup 1.0000x reference)
//
#include <hip/hip_runtime.h>
#include <stdint.h>

// Problem dims (fixed)
#define BB 64
#define TT 32
#define EE 512
#define HH 512
#define VV 32000
#define G4 2048

typedef __bf16 bf16x8 __attribute__((ext_vector_type(8)));
typedef float f32x4 __attribute__((ext_vector_type(4)));

__device__ __forceinline__ unsigned short f2bf(float f) {
  unsigned int u = __builtin_bit_cast(unsigned int, f);
  u += 0x7FFFu + ((u >> 16) & 1u);   // RNE
  return (unsigned short)(u >> 16);
}
__device__ __forceinline__ float bf2f(unsigned short h) {
  unsigned int u = ((unsigned int)h) << 16;
  return __builtin_bit_cast(float, u);
}
__device__ __forceinline__ void gload_lds16(const unsigned short* g, unsigned short* l) {
  __builtin_amdgcn_global_load_lds((const __attribute__((address_space(1))) void*)g,
                                   (__attribute__((address_space(3))) void*)l, 16, 0, 0);
}
__device__ __forceinline__ float sigm(float x) { return 1.f / (1.f + __expf(-x)); }
__device__ __forceinline__ float tanh_fast(float x) {
  return 1.f - 2.f / (__expf(2.f * x) + 1.f);   // stable at +-inf
}
__device__ __forceinline__ unsigned int pack_hn(float hn) {
  unsigned short hi = f2bf(hn);
  unsigned short lo = f2bf(hn - bf2f(hi));
  return ((unsigned int)hi << 16) | (unsigned int)lo;
}

// ---------------------------------------------------------------------------
// Kernel 1: Gpre(2112 x 2048) = [feat; emb[cap]] @ W_ih.T + (b_ih + b_hh) [fp32]
// ---------------------------------------------------------------------------
__global__ __launch_bounds__(256) void k_gemm_ih(const float* __restrict__ feat,
                                                 const int* __restrict__ cap,
                                                 const float* __restrict__ emb,
                                                 const float* __restrict__ Bw,
                                                 const float* __restrict__ bih,
                                                 const float* __restrict__ bhh,
                                                 float* __restrict__ C) {
  __shared__ float As[16][128];
  __shared__ float Bs[16][128];
  const int tid = threadIdx.x;
  const int bx = blockIdx.x & 15;   // n tile 0..15
  const int by = blockIdx.x >> 4;   // m tile 0..16
  const int m0 = by * 128, n0 = bx * 128;
  const int tx = tid & 15, ty = tid >> 4;

  float acc[8][8];
#pragma unroll
  for (int i = 0; i < 8; i++)
#pragma unroll
    for (int j = 0; j < 8; j++) acc[i][j] = 0.f;

  const int lr = tid >> 1;           // row-in-tile 0..127
  const int lk = (tid & 1) * 8;      // 0 or 8
  int arow = m0 + lr; if (arow > 2111) arow = 2111;  // clamp (store guarded)
  const float* Ap;
  if (arow < BB) {
    Ap = feat + (size_t)arow * EE + lk;
  } else {
    int idx = arow - BB;
    int t = idx >> 6, b = idx & 63;
    Ap = emb + (size_t)cap[b * TT + t] * EE + lk;
  }
  const int brow = n0 + lr;          // < 2048 always
  const float* Bp = Bw + (size_t)brow * EE + lk;

  for (int k0 = 0; k0 < EE; k0 += 16) {
    float4 a0 = *(const float4*)(Ap + k0);
    float4 a1 = *(const float4*)(Ap + k0 + 4);
    float4 b0 = *(const float4*)(Bp + k0);
    float4 b1 = *(const float4*)(Bp + k0 + 4);
    __syncthreads();
    As[lk + 0][lr] = a0.x; As[lk + 1][lr] = a0.y; As[lk + 2][lr] = a0.z; As[lk + 3][lr] = a0.w;
    As[lk + 4][lr] = a1.x; As[lk + 5][lr] = a1.y; As[lk + 6][lr] = a1.z; As[lk + 7][lr] = a1.w;
    Bs[lk + 0][lr] = b0.x; Bs[lk + 1][lr] = b0.y; Bs[lk + 2][lr] = b0.z; Bs[lk + 3][lr] = b0.w;
    Bs[lk + 4][lr] = b1.x; Bs[lk + 5][lr] = b1.y; Bs[lk + 6][lr] = b1.z; Bs[lk + 7][lr] = b1.w;
    __syncthreads();
#pragma unroll
    for (int k = 0; k < 16; k++) {
      float a[8], b[8];
      *(float4*)&a[0] = *(const float4*)&As[k][ty * 8];
      *(float4*)&a[4] = *(const float4*)&As[k][ty * 8 + 4];
      *(float4*)&b[0] = *(const float4*)&Bs[k][tx * 8];
      *(float4*)&b[4] = *(const float4*)&Bs[k][tx * 8 + 4];
#pragma unroll
      for (int i = 0; i < 8; i++)
#pragma unroll
        for (int j = 0; j < 8; j++) acc[i][j] += a[i] * b[j];
    }
  }

  float bs[8];
#pragma unroll
  for (int j = 0; j < 8; j++) {
    int n = n0 + tx * 8 + j;
    bs[j] = bih[n] + bhh[n];
  }
#pragma unroll
  for (int i = 0; i < 8; i++) {
    int m = m0 + ty * 8 + i;
    if (m < 2112) {
      float4 o0, o1;
      o0.x = acc[i][0] + bs[0]; o0.y = acc[i][1] + bs[1];
      o0.z = acc[i][2] + bs[2]; o0.w = acc[i][3] + bs[3];
      o1.x = acc[i][4] + bs[4]; o1.y = acc[i][5] + bs[5];
      o1.z = acc[i][6] + bs[6]; o1.w = acc[i][7] + bs[7];
      *(float4*)(C + (size_t)m * G4 + n0 + tx * 8) = o0;
      *(float4*)(C + (size_t)m * G4 + n0 + tx * 8 + 4) = o1;
    }
  }
}

// ---------------------------------------------------------------------------
// Kernel 2: cast W_out f32 -> bf16
// ---------------------------------------------------------------------------
__global__ void k_cast(const float* __restrict__ src, unsigned short* __restrict__ dst, int n4) {
  int i = blockIdx.x * blockDim.x + threadIdx.x;
  int stride = gridDim.x * blockDim.x;
  for (; i < n4; i += stride) {
    float4 v = ((const float4*)src)[i];
    ushort4 o;
    o.x = f2bf(v.x); o.y = f2bf(v.y); o.z = f2bf(v.z); o.w = f2bf(v.w);
    ((ushort4*)dst)[i] = o;
  }
}

// ---------------------------------------------------------------------------
// Kernel 3: zero the barrier flags at the coherence point (agent atomics)
// ---------------------------------------------------------------------------
__global__ void k_zero(int* flags) {
  __hip_atomic_store(&flags[threadIdx.x], 0, __ATOMIC_RELAXED, __HIP_MEMORY_SCOPE_AGENT);
}

// ---------------------------------------------------------------------------
// Fence-FREE device barrier for 64 co-resident blocks.  All cross-block data
// (h, flags) moves via relaxed agent-scope atomics (sc0/sc1 -> L1/L2 bypass,
// served at the coherence point), so no L2 writeback/invalidate is needed.
// Ordering: per-wave s_waitcnt vmcnt(0) drains the h atomic-stores (they are
// at the coherence point once ack'd), barrier joins all waves, then the flag
// store is issued.  Pollers spin on relaxed atomic loads.
// ---------------------------------------------------------------------------
__device__ __forceinline__ void gridbar_nf(int* flags, int id) {
  asm volatile("s_waitcnt vmcnt(0)" ::: "memory");
  __syncthreads();
  if (threadIdx.x == 0)
    __hip_atomic_store(&flags[blockIdx.x], id, __ATOMIC_RELAXED, __HIP_MEMORY_SCOPE_AGENT);
  if (threadIdx.x < 64) {
    while (__hip_atomic_load(&flags[threadIdx.x], __ATOMIC_RELAXED, __HIP_MEMORY_SCOPE_AGENT) < id)
      __builtin_amdgcn_s_sleep(1);
  }
  __syncthreads();
}

// ---------------------------------------------------------------------------
// Kernel 4: persistent LSTM recurrence (prime + 32 steps, one launch).
// 64 blocks x 256 thr. Block owns u0=bid*8 (8 u x 4 gates). W_hh split to
// bf16 hi/lo ONCE into LDS (64 KB), gate-packed frags [i|f],[g|o].
// h exchanged through hseq[s][b][u] as packed u32 (hi<<16|lo) via relaxed
// agent atomics (never rewritten within a launch -> no staleness; replays
// rewrite identical values -> benign). c state in registers.
// hall (bf16 hi) stored b-major via normal stores (inter-kernel coherence).
// ---------------------------------------------------------------------------
__global__ __launch_bounds__(256) void k_rnn(const float* __restrict__ Gpre,
                                             const float* __restrict__ Whh,
                                             unsigned int* __restrict__ hseq,
                                             unsigned short* __restrict__ hall,
                                             int* __restrict__ flags) {
  __shared__ __align__(16) unsigned short Wl[2][2][16][512];  // [frag][hi/lo][row][k] = 64 KB
  const int tid = threadIdx.x;
  const int bid = blockIdx.x;
  const int u0 = bid * 8;
  const int l = tid & 63;
  const int w = tid >> 6;
  const int lr = l & 15;
  const int kc = l >> 4;          // 0..3
  const bool lowh = (lr < 8);
  const int u = u0 + (lr & 7);

  // ---- stage W_hh -> LDS (split hi/lo on the fly), 2048 16B-chunk tasks ----
#pragma unroll
  for (int it = 0; it < 8; ++it) {
    int id = it * 256 + tid;        // 0..2047
    int fr = id >> 10;              // frag 0 = gates{i,f}, 1 = {g,o}
    int r = (id >> 6) & 15;         // packed row
    int c = id & 63;                // 16B chunk (8 f32 source elems)
    int gate = fr * 2 + (r >> 3);
    int gr = gate * HH + u0 + (r & 7);
    const float* src = Whh + (size_t)gr * HH + c * 8;
    float4 v0 = *(const float4*)src;
    float4 v1 = *(const float4*)(src + 4);
    float vv[8] = {v0.x, v0.y, v0.z, v0.w, v1.x, v1.y, v1.z, v1.w};
    __align__(16) unsigned short hi8[8];
    __align__(16) unsigned short lo8[8];
#pragma unroll
    for (int e = 0; e < 8; ++e) {
      hi8[e] = f2bf(vv[e]);
      lo8[e] = f2bf(vv[e] - bf2f(hi8[e]));
    }
    int cs = c ^ (r & 7);
    *(int4*)&Wl[fr][0][r][cs * 8] = *(const int4*)hi8;
    *(int4*)&Wl[fr][1][r][cs * 8] = *(const int4*)lo8;
  }

  // ---- prime step (h=c=0): elementwise from Gpre rows 0..63 ----
  float c_reg[4];
#pragma unroll
  for (int j = 0; j < 4; ++j) {
    int b = w * 16 + kc * 4 + j;
    const float* gp = Gpre + (size_t)b * G4;
    float gi = gp[u], gg = gp[1024 + u], go = gp[1536 + u];
    float cn = sigm(gi) * tanh_fast(gg);
    float hn = sigm(go) * tanh_fast(cn);
    c_reg[j] = cn;
    if (lowh)
      __hip_atomic_store(&hseq[(size_t)b * HH + u], pack_hn(hn),
                         __ATOMIC_RELAXED, __HIP_MEMORY_SCOPE_AGENT);
  }
  gridbar_nf(flags, 1);   // also covers LDS staging via its __syncthreads

  // ---- 32 recurrent steps ----
  for (int s = 1; s <= TT; ++s) {
    unsigned int* hin = hseq + (size_t)(s - 1) * BB * HH;
    unsigned int* hout = hseq + (size_t)s * BB * HH;

    const f32x4 vz = {0.f, 0.f, 0.f, 0.f};
    f32x4 acc0 = vz, acc1 = vz;
    const size_t a_off = (size_t)(w * 16 + lr) * HH + kc * 8;
#pragma unroll
    for (int t = 0; t < 16; ++t) {
      unsigned long long* hp = (unsigned long long*)(hin + a_off + t * 32);
      unsigned long long q0 = __hip_atomic_load(hp + 0, __ATOMIC_RELAXED, __HIP_MEMORY_SCOPE_AGENT);
      unsigned long long q1 = __hip_atomic_load(hp + 1, __ATOMIC_RELAXED, __HIP_MEMORY_SCOPE_AGENT);
      unsigned long long q2 = __hip_atomic_load(hp + 2, __ATOMIC_RELAXED, __HIP_MEMORY_SCOPE_AGENT);
      unsigned long long q3 = __hip_atomic_load(hp + 3, __ATOMIC_RELAXED, __HIP_MEMORY_SCOPE_AGENT);
      union { unsigned int w4[4]; bf16x8 v; } uh, ul;
      unsigned long long qq[4] = {q0, q1, q2, q3};
#pragma unroll
      for (int r = 0; r < 4; ++r) {
        unsigned int e0 = (unsigned int)qq[r];
        unsigned int e1 = (unsigned int)(qq[r] >> 32);
        uh.w4[r] = (e0 >> 16) | (e1 & 0xFFFF0000u);
        ul.w4[r] = (e0 & 0xFFFFu) | (e1 << 16);
      }
      bf16x8 ah = uh.v;
      bf16x8 al = ul.v;
      int cs = (t * 4 + kc) ^ (lr & 7);
      bf16x8 b0h = *(const bf16x8*)&Wl[0][0][lr][cs * 8];
      bf16x8 b0l = *(const bf16x8*)&Wl[0][1][lr][cs * 8];
      bf16x8 b1h = *(const bf16x8*)&Wl[1][0][lr][cs * 8];
      bf16x8 b1l = *(const bf16x8*)&Wl[1][1][lr][cs * 8];
      acc0 = __builtin_amdgcn_mfma_f32_16x16x32_bf16(ah, b0h, acc0, 0, 0, 0);
      acc0 = __builtin_amdgcn_mfma_f32_16x16x32_bf16(al, b0h, acc0, 0, 0, 0);
      acc0 = __builtin_amdgcn_mfma_f32_16x16x32_bf16(ah, b0l, acc0, 0, 0, 0);
      acc1 = __builtin_amdgcn_mfma_f32_16x16x32_bf16(ah, b1h, acc1, 0, 0, 0);
      acc1 = __builtin_amdgcn_mfma_f32_16x16x32_bf16(al, b1h, acc1, 0, 0, 0);
      acc1 = __builtin_amdgcn_mfma_f32_16x16x32_bf16(ah, b1l, acc1, 0, 0, 0);
    }

    // epilogue: lane lr holds gate (lr<8 ? i : f) in acc0, (g : o) in acc1
#pragma unroll
    for (int j = 0; j < 4; ++j) {
      int b = w * 16 + kc * 4 + j;
      float my0 = acc0[j], my1 = acc1[j];
      float p0 = __shfl_xor(my0, 8);
      float p1 = __shfl_xor(my1, 8);
      float i_ = lowh ? my0 : p0;
      float f_ = lowh ? p0 : my0;
      float g_ = lowh ? my1 : p1;
      float o_ = lowh ? p1 : my1;
      const float* gp = Gpre + (size_t)(s * 64 + b) * G4;
      i_ += gp[u]; f_ += gp[512 + u]; g_ += gp[1024 + u]; o_ += gp[1536 + u];
      float cn = sigm(f_) * c_reg[j] + sigm(i_) * tanh_fast(g_);
      float hn = sigm(o_) * tanh_fast(cn);
      c_reg[j] = cn;
      if (lowh) {
        __hip_atomic_store(&hout[(size_t)b * HH + u], pack_hn(hn),
                           __ATOMIC_RELAXED, __HIP_MEMORY_SCOPE_AGENT);
        hall[((size_t)b * TT + (s - 1)) * HH + u] = f2bf(hn);
      }
    }
    if (s < TT) gridbar_nf(flags, s + 1);
  }
}

// ---------------------------------------------------------------------------
// Kernel 5: Out(2048 x 32000) = hall @ W_out.T + b_out  [bf16 MFMA, f32 out]
// (unchanged — verified)
// ---------------------------------------------------------------------------
__global__ __launch_bounds__(256) void k_gemm_out(const unsigned short* __restrict__ Xb,
                                                  const unsigned short* __restrict__ Wb,
                                                  const float* __restrict__ bout,
                                                  float* __restrict__ out) {
  __shared__ __align__(16) unsigned short As[128 * 64];
  __shared__ __align__(16) unsigned short Bs[128 * 64];
  const int tid = threadIdx.x;
  int bid = blockIdx.x;
  int swz = (bid & 7) * 500 + (bid >> 3);  // 8 XCDs x 500-block chunks
  const int mt = swz & 15;
  const int nt = swz >> 4;
  const int l = tid & 63;
  const int w = tid >> 6;
  const int wr = (w >> 1) * 64;
  const int wc = (w & 1) * 64;

  const f32x4 vz = {0.f, 0.f, 0.f, 0.f};
  f32x4 acc[4][4];
#pragma unroll
  for (int m = 0; m < 4; m++)
#pragma unroll
    for (int n = 0; n < 4; n++) acc[m][n] = vz;

  const int srow = tid >> 3;
  const int scs = tid & 7;
  const unsigned short* ga0 = Xb + (size_t)(mt * 128) * EE;
  const unsigned short* gb0 = Wb + (size_t)(nt * 128) * EE;

  for (int kt = 0; kt < 8; kt++) {
    if (kt) __syncthreads();
#pragma unroll
    for (int i = 0; i < 4; i++) {
      int row = i * 32 + srow;
      int cb = scs ^ (row & 7);
      gload_lds16(ga0 + (size_t)row * EE + kt * 64 + cb * 8, &As[row * 64 + scs * 8]);
      gload_lds16(gb0 + (size_t)row * EE + kt * 64 + cb * 8, &Bs[row * 64 + scs * 8]);
    }
    __syncthreads();
#pragma unroll
    for (int kk = 0; kk < 2; kk++) {
      bf16x8 af[4], bfr[4];
#pragma unroll
      for (int m = 0; m < 4; m++) {
        int row = wr + m * 16 + (l & 15);
        int cc = kk * 4 + (l >> 4);
        int cs = cc ^ (row & 7);
        af[m] = *(const bf16x8*)&As[row * 64 + cs * 8];
      }
#pragma unroll
      for (int n = 0; n < 4; n++) {
        int row = wc + n * 16 + (l & 15);
        int cc = kk * 4 + (l >> 4);
        int cs = cc ^ (row & 7);
        bfr[n] = *(const bf16x8*)&Bs[row * 64 + cs * 8];
      }
#pragma unroll
      for (int m = 0; m < 4; m++)
#pragma unroll
        for (int n = 0; n < 4; n++)
          acc[m][n] = __builtin_amdgcn_mfma_f32_16x16x32_bf16(bfr[n], af[m], acc[m][n], 0, 0, 0);
    }
  }

  float4 bo4[4];
#pragma unroll
  for (int n = 0; n < 4; n++)
    bo4[n] = *(const float4*)(bout + nt * 128 + wc + n * 16 + (l >> 4) * 4);
#pragma unroll
  for (int m = 0; m < 4; m++) {
    float* orow = out + (size_t)(mt * 128 + wr + m * 16 + (l & 15)) * VV
                      + nt * 128 + wc + (l >> 4) * 4;
#pragma unroll
    for (int n = 0; n < 4; n++) {
      float4 v;
      v.x = acc[m][n][0] + bo4[n].x;
      v.y = acc[m][n][1] + bo4[n].y;
      v.z = acc[m][n][2] + bo4[n].z;
      v.w = acc[m][n][3] + bo4[n].w;
      *(float4*)(orow + n * 16) = v;
    }
  }
}

// ---------------------------------------------------------------------------
extern "C" void kernel_launch(void* const* d_in, const int* in_sizes, int n_in,
                              void* d_out, int out_size, void* d_ws, size_t ws_size,
                              hipStream_t stream) {
  const float* feat = (const float*)d_in[0];
  const int* cap = (const int*)d_in[1];
  // d_in[2] = seq_len (constant 32)
  const float* emb = (const float*)d_in[3];
  const float* Wih = (const float*)d_in[4];
  const float* Whh = (const float*)d_in[5];
  const float* bih = (const float*)d_in[6];
  const float* bhh = (const float*)d_in[7];
  const float* Wout = (const float*)d_in[8];
  const float* bout = (const float*)d_in[9];
  float* out = (float*)d_out;

  char* ws = (char*)d_ws;
  float* Gpre = (float*)ws;                                   // 17,301,504
  unsigned short* hall = (unsigned short*)(ws + 17301504);    //  2,097,152 (b-major)
  unsigned short* Wb = (unsigned short*)(ws + 19398656);      // 32,768,000
  unsigned int* hseq = (unsigned int*)(ws + 52166656);        //  4,325,376 (33 steps)
  int* flags = (int*)(ws + 56492032);                         //        256

  k_zero<<<dim3(1), dim3(64), 0, stream>>>(flags);
  k_gemm_ih<<<dim3(17 * 16), dim3(256), 0, stream>>>(feat, cap, emb, Wih, bih, bhh, Gpre);
  k_cast<<<dim3(2048), dim3(256), 0, stream>>>(Wout, Wb, (VV * HH) / 4);
  k_rnn<<<dim3(64), dim3(256), 0, stream>>>(Gpre, Whh, hseq, hall, flags);
  k_gemm_out<<<dim3(4000), dim3(256), 0, stream>>>(hall, Wb, bout, out);
}

// Round 5
// 557.976 us; speedup vs baseline: 1.2031x; 1.2031x over previous
//
#include <hip/hip_runtime.h>
#include <stdint.h>

// Problem dims (fixed)
#define BB 64
#define TT 32
#define EE 512
#define HH 512
#define VV 32000
#define G4 2048

typedef __bf16 bf16x8 __attribute__((ext_vector_type(8)));
typedef float f32x4 __attribute__((ext_vector_type(4)));

__device__ __forceinline__ unsigned short f2bf(float f) {
  unsigned int u = __builtin_bit_cast(unsigned int, f);
  u += 0x7FFFu + ((u >> 16) & 1u);   // RNE
  return (unsigned short)(u >> 16);
}
__device__ __forceinline__ float bf2f(unsigned short h) {
  unsigned int u = ((unsigned int)h) << 16;
  return __builtin_bit_cast(float, u);
}
__device__ __forceinline__ void gload_lds16(const unsigned short* g, unsigned short* l) {
  __builtin_amdgcn_global_load_lds((const __attribute__((address_space(1))) void*)g,
                                   (__attribute__((address_space(3))) void*)l, 16, 0, 0);
}
__device__ __forceinline__ float sigm(float x) { return 1.f / (1.f + __expf(-x)); }
__device__ __forceinline__ float tanh_fast(float x) {
  return 1.f - 2.f / (__expf(2.f * x) + 1.f);   // stable at +-inf
}
__device__ __forceinline__ unsigned int pack_hn(float hn) {
  unsigned short hi = f2bf(hn);
  unsigned short lo = f2bf(hn - bf2f(hi));
  return ((unsigned int)hi << 16) | (unsigned int)lo;
}

// ---------------------------------------------------------------------------
// Kernel 1: Gpre(2112 x 2048) = [feat; emb[cap]] @ W_ih.T + (b_ih + b_hh) [fp32]
// ---------------------------------------------------------------------------
__global__ __launch_bounds__(256) void k_gemm_ih(const float* __restrict__ feat,
                                                 const int* __restrict__ cap,
                                                 const float* __restrict__ emb,
                                                 const float* __restrict__ Bw,
                                                 const float* __restrict__ bih,
                                                 const float* __restrict__ bhh,
                                                 float* __restrict__ C) {
  __shared__ float As[16][128];
  __shared__ float Bs[16][128];
  const int tid = threadIdx.x;
  const int bx = blockIdx.x & 15;   // n tile 0..15
  const int by = blockIdx.x >> 4;   // m tile 0..16
  const int m0 = by * 128, n0 = bx * 128;
  const int tx = tid & 15, ty = tid >> 4;

  float acc[8][8];
#pragma unroll
  for (int i = 0; i < 8; i++)
#pragma unroll
    for (int j = 0; j < 8; j++) acc[i][j] = 0.f;

  const int lr = tid >> 1;           // row-in-tile 0..127
  const int lk = (tid & 1) * 8;      // 0 or 8
  int arow = m0 + lr; if (arow > 2111) arow = 2111;  // clamp (store guarded)
  const float* Ap;
  if (arow < BB) {
    Ap = feat + (size_t)arow * EE + lk;
  } else {
    int idx = arow - BB;
    int t = idx >> 6, b = idx & 63;
    Ap = emb + (size_t)cap[b * TT + t] * EE + lk;
  }
  const int brow = n0 + lr;          // < 2048 always
  const float* Bp = Bw + (size_t)brow * EE + lk;

  for (int k0 = 0; k0 < EE; k0 += 16) {
    float4 a0 = *(const float4*)(Ap + k0);
    float4 a1 = *(const float4*)(Ap + k0 + 4);
    float4 b0 = *(const float4*)(Bp + k0);
    float4 b1 = *(const float4*)(Bp + k0 + 4);
    __syncthreads();
    As[lk + 0][lr] = a0.x; As[lk + 1][lr] = a0.y; As[lk + 2][lr] = a0.z; As[lk + 3][lr] = a0.w;
    As[lk + 4][lr] = a1.x; As[lk + 5][lr] = a1.y; As[lk + 6][lr] = a1.z; As[lk + 7][lr] = a1.w;
    Bs[lk + 0][lr] = b0.x; Bs[lk + 1][lr] = b0.y; Bs[lk + 2][lr] = b0.z; Bs[lk + 3][lr] = b0.w;
    Bs[lk + 4][lr] = b1.x; Bs[lk + 5][lr] = b1.y; Bs[lk + 6][lr] = b1.z; Bs[lk + 7][lr] = b1.w;
    __syncthreads();
#pragma unroll
    for (int k = 0; k < 16; k++) {
      float a[8], b[8];
      *(float4*)&a[0] = *(const float4*)&As[k][ty * 8];
      *(float4*)&a[4] = *(const float4*)&As[k][ty * 8 + 4];
      *(float4*)&b[0] = *(const float4*)&Bs[k][tx * 8];
      *(float4*)&b[4] = *(const float4*)&Bs[k][tx * 8 + 4];
#pragma unroll
      for (int i = 0; i < 8; i++)
#pragma unroll
        for (int j = 0; j < 8; j++) acc[i][j] += a[i] * b[j];
    }
  }

  float bs[8];
#pragma unroll
  for (int j = 0; j < 8; j++) {
    int n = n0 + tx * 8 + j;
    bs[j] = bih[n] + bhh[n];
  }
#pragma unroll
  for (int i = 0; i < 8; i++) {
    int m = m0 + ty * 8 + i;
    if (m < 2112) {
      float4 o0, o1;
      o0.x = acc[i][0] + bs[0]; o0.y = acc[i][1] + bs[1];
      o0.z = acc[i][2] + bs[2]; o0.w = acc[i][3] + bs[3];
      o1.x = acc[i][4] + bs[4]; o1.y = acc[i][5] + bs[5];
      o1.z = acc[i][6] + bs[6]; o1.w = acc[i][7] + bs[7];
      *(float4*)(C + (size_t)m * G4 + n0 + tx * 8) = o0;
      *(float4*)(C + (size_t)m * G4 + n0 + tx * 8 + 4) = o1;
    }
  }
}

// ---------------------------------------------------------------------------
// Kernel 2: cast W_out f32 -> bf16
// ---------------------------------------------------------------------------
__global__ void k_cast(const float* __restrict__ src, unsigned short* __restrict__ dst, int n4) {
  int i = blockIdx.x * blockDim.x + threadIdx.x;
  int stride = gridDim.x * blockDim.x;
  for (; i < n4; i += stride) {
    float4 v = ((const float4*)src)[i];
    ushort4 o;
    o.x = f2bf(v.x); o.y = f2bf(v.y); o.z = f2bf(v.z); o.w = f2bf(v.w);
    ((ushort4*)dst)[i] = o;
  }
}

// ---------------------------------------------------------------------------
// Kernel 3: zero the barrier flags at the coherence point (agent atomics)
// ---------------------------------------------------------------------------
__global__ void k_zero(int* flags) {
  __hip_atomic_store(&flags[threadIdx.x], 0, __ATOMIC_RELAXED, __HIP_MEMORY_SCOPE_AGENT);
}

// ---------------------------------------------------------------------------
// Fence-free device barrier for 64 co-resident blocks.  Cross-block h data is
// WRITTEN with relaxed agent atomics (bypass to coherence point) but READ with
// normal cached loads (safe: a reader never touches an hseq[s] line before
// this barrier; L2s are invalidated at dispatch start, so any post-barrier L2
// miss fetches the coherence-point value and L2 hits are post-barrier copies).
// The inline s_waitcnt vmcnt(0) drains h-stores AND Gpre prefetch loads before
// the arrival flag; pollers spin on relaxed atomic flag loads.
// ---------------------------------------------------------------------------
__device__ __forceinline__ void gridbar_nf(int* flags, int id) {
  asm volatile("s_waitcnt vmcnt(0)" ::: "memory");
  __syncthreads();
  if (threadIdx.x == 0)
    __hip_atomic_store(&flags[blockIdx.x], id, __ATOMIC_RELAXED, __HIP_MEMORY_SCOPE_AGENT);
  if (threadIdx.x < 64) {
    while (__hip_atomic_load(&flags[threadIdx.x], __ATOMIC_RELAXED, __HIP_MEMORY_SCOPE_AGENT) < id)
      __builtin_amdgcn_s_sleep(1);
  }
  __syncthreads();
}

// ---------------------------------------------------------------------------
// Kernel 4: persistent LSTM recurrence (prime + 32 steps, one launch).
// 64 blocks x 256 thr. Block owns u0=bid*8 (8 u x 4 gates). W_hh split to
// bf16 hi/lo ONCE into LDS (64 KB), gate-packed frags [i|f],[g|o].
// h exchanged via hseq[s][b][u] packed u32 (hi<<16|lo): atomic stores,
// PLAIN pipelined loads (L2-shared per XCD).  Gpre gate rows for step s+1
// are prefetched into registers BEFORE the barrier (latency hides under
// arrival/poll).  c state in registers.  hall (bf16 hi) stored b-major.
// ---------------------------------------------------------------------------
__global__ __launch_bounds__(256) void k_rnn(const float* __restrict__ Gpre,
                                             const float* __restrict__ Whh,
                                             unsigned int* __restrict__ hseq,
                                             unsigned short* __restrict__ hall,
                                             int* __restrict__ flags) {
  __shared__ __align__(16) unsigned short Wl[2][2][16][512];  // [frag][hi/lo][row][k] = 64 KB
  const int tid = threadIdx.x;
  const int bid = blockIdx.x;
  const int u0 = bid * 8;
  const int l = tid & 63;
  const int w = tid >> 6;
  const int lr = l & 15;
  const int kc = l >> 4;          // 0..3
  const bool lowh = (lr < 8);
  const int u = u0 + (lr & 7);

  // ---- stage W_hh -> LDS (split hi/lo on the fly), 2048 16B-chunk tasks ----
#pragma unroll
  for (int it = 0; it < 8; ++it) {
    int id = it * 256 + tid;        // 0..2047
    int fr = id >> 10;              // frag 0 = gates{i,f}, 1 = {g,o}
    int r = (id >> 6) & 15;         // packed row
    int c = id & 63;                // 16B chunk (8 f32 source elems)
    int gate = fr * 2 + (r >> 3);
    int gr = gate * HH + u0 + (r & 7);
    const float* src = Whh + (size_t)gr * HH + c * 8;
    float4 v0 = *(const float4*)src;
    float4 v1 = *(const float4*)(src + 4);
    float vv[8] = {v0.x, v0.y, v0.z, v0.w, v1.x, v1.y, v1.z, v1.w};
    __align__(16) unsigned short hi8[8];
    __align__(16) unsigned short lo8[8];
#pragma unroll
    for (int e = 0; e < 8; ++e) {
      hi8[e] = f2bf(vv[e]);
      lo8[e] = f2bf(vv[e] - bf2f(hi8[e]));
    }
    int cs = c ^ (r & 7);
    *(int4*)&Wl[fr][0][r][cs * 8] = *(const int4*)hi8;
    *(int4*)&Wl[fr][1][r][cs * 8] = *(const int4*)lo8;
  }

  // ---- prime step (h=c=0): elementwise from Gpre rows 0..63 ----
  float c_reg[4];
#pragma unroll
  for (int j = 0; j < 4; ++j) {
    int b = w * 16 + kc * 4 + j;
    const float* gp = Gpre + (size_t)b * G4;
    float gi = gp[u], gg = gp[1024 + u], go = gp[1536 + u];
    float cn = sigm(gi) * tanh_fast(gg);
    float hn = sigm(go) * tanh_fast(cn);
    c_reg[j] = cn;
    if (lowh)
      __hip_atomic_store(&hseq[(size_t)b * HH + u], pack_hn(hn),
                         __ATOMIC_RELAXED, __HIP_MEMORY_SCOPE_AGENT);
  }

  // ---- prefetch Gpre gate rows for step 1 (drains at the barrier fence) ----
  float pre[4][4];   // [gate][j] — statically indexed after unroll
#pragma unroll
  for (int j = 0; j < 4; ++j) {
    int b = w * 16 + kc * 4 + j;
    const float* gp = Gpre + (size_t)(1 * 64 + b) * G4;
    pre[0][j] = gp[u];
    pre[1][j] = gp[512 + u];
    pre[2][j] = gp[1024 + u];
    pre[3][j] = gp[1536 + u];
  }
  gridbar_nf(flags, 1);   // also covers LDS staging via its __syncthreads

  // ---- 32 recurrent steps ----
  for (int s = 1; s <= TT; ++s) {
    const unsigned int* hin = hseq + (size_t)(s - 1) * BB * HH;
    unsigned int* hout = hseq + (size_t)s * BB * HH;

    const f32x4 vz = {0.f, 0.f, 0.f, 0.f};
    f32x4 acc0 = vz, acc1 = vz;
    const size_t a_off = (size_t)(w * 16 + lr) * HH + kc * 8;
#pragma unroll
    for (int t = 0; t < 16; ++t) {
      const uint4* hp4 = (const uint4*)(hin + a_off + t * 32);
      union { uint4 q[2]; unsigned int e[8]; } U;
      U.q[0] = hp4[0];
      U.q[1] = hp4[1];
      union { unsigned int w4[4]; bf16x8 v; } uh, ul;
#pragma unroll
      for (int r = 0; r < 4; ++r) {
        unsigned int e0 = U.e[2 * r], e1 = U.e[2 * r + 1];
        uh.w4[r] = (e0 >> 16) | (e1 & 0xFFFF0000u);
        ul.w4[r] = (e0 & 0xFFFFu) | (e1 << 16);
      }
      bf16x8 ah = uh.v;
      bf16x8 al = ul.v;
      int cs = (t * 4 + kc) ^ (lr & 7);
      bf16x8 b0h = *(const bf16x8*)&Wl[0][0][lr][cs * 8];
      bf16x8 b0l = *(const bf16x8*)&Wl[0][1][lr][cs * 8];
      bf16x8 b1h = *(const bf16x8*)&Wl[1][0][lr][cs * 8];
      bf16x8 b1l = *(const bf16x8*)&Wl[1][1][lr][cs * 8];
      acc0 = __builtin_amdgcn_mfma_f32_16x16x32_bf16(ah, b0h, acc0, 0, 0, 0);
      acc0 = __builtin_amdgcn_mfma_f32_16x16x32_bf16(al, b0h, acc0, 0, 0, 0);
      acc0 = __builtin_amdgcn_mfma_f32_16x16x32_bf16(ah, b0l, acc0, 0, 0, 0);
      acc1 = __builtin_amdgcn_mfma_f32_16x16x32_bf16(ah, b1h, acc1, 0, 0, 0);
      acc1 = __builtin_amdgcn_mfma_f32_16x16x32_bf16(al, b1h, acc1, 0, 0, 0);
      acc1 = __builtin_amdgcn_mfma_f32_16x16x32_bf16(ah, b1l, acc1, 0, 0, 0);
    }

    // epilogue: lane lr holds gate (lr<8 ? i : f) in acc0, (g : o) in acc1
#pragma unroll
    for (int j = 0; j < 4; ++j) {
      int b = w * 16 + kc * 4 + j;
      float my0 = acc0[j], my1 = acc1[j];
      float p0 = __shfl_xor(my0, 8);
      float p1 = __shfl_xor(my1, 8);
      float i_ = (lowh ? my0 : p0) + pre[0][j];
      float f_ = (lowh ? p0 : my0) + pre[1][j];
      float g_ = (lowh ? my1 : p1) + pre[2][j];
      float o_ = (lowh ? p1 : my1) + pre[3][j];
      float cn = sigm(f_) * c_reg[j] + sigm(i_) * tanh_fast(g_);
      float hn = sigm(o_) * tanh_fast(cn);
      c_reg[j] = cn;
      if (lowh) {
        __hip_atomic_store(&hout[(size_t)b * HH + u], pack_hn(hn),
                           __ATOMIC_RELAXED, __HIP_MEMORY_SCOPE_AGENT);
        hall[((size_t)b * TT + (s - 1)) * HH + u] = f2bf(hn);
      }
    }

    if (s < TT) {
      // prefetch Gpre for step s+1 (overlaps with barrier arrival/poll)
#pragma unroll
      for (int j = 0; j < 4; ++j) {
        int b = w * 16 + kc * 4 + j;
        const float* gp = Gpre + (size_t)((s + 1) * 64 + b) * G4;
        pre[0][j] = gp[u];
        pre[1][j] = gp[512 + u];
        pre[2][j] = gp[1024 + u];
        pre[3][j] = gp[1536 + u];
      }
      gridbar_nf(flags, s + 1);
    }
  }
}

// ---------------------------------------------------------------------------
// Kernel 5: Out(2048 x 32000) = hall @ W_out.T + b_out  [bf16 MFMA, f32 out]
// (unchanged — verified)
// ---------------------------------------------------------------------------
__global__ __launch_bounds__(256) void k_gemm_out(const unsigned short* __restrict__ Xb,
                                                  const unsigned short* __restrict__ Wb,
                                                  const float* __restrict__ bout,
                                                  float* __restrict__ out) {
  __shared__ __align__(16) unsigned short As[128 * 64];
  __shared__ __align__(16) unsigned short Bs[128 * 64];
  const int tid = threadIdx.x;
  int bid = blockIdx.x;
  int swz = (bid & 7) * 500 + (bid >> 3);  // 8 XCDs x 500-block chunks
  const int mt = swz & 15;
  const int nt = swz >> 4;
  const int l = tid & 63;
  const int w = tid >> 6;
  const int wr = (w >> 1) * 64;
  const int wc = (w & 1) * 64;

  const f32x4 vz = {0.f, 0.f, 0.f, 0.f};
  f32x4 acc[4][4];
#pragma unroll
  for (int m = 0; m < 4; m++)
#pragma unroll
    for (int n = 0; n < 4; n++) acc[m][n] = vz;

  const int srow = tid >> 3;
  const int scs = tid & 7;
  const unsigned short* ga0 = Xb + (size_t)(mt * 128) * EE;
  const unsigned short* gb0 = Wb + (size_t)(nt * 128) * EE;

  for (int kt = 0; kt < 8; kt++) {
    if (kt) __syncthreads();
#pragma unroll
    for (int i = 0; i < 4; i++) {
      int row = i * 32 + srow;
      int cb = scs ^ (row & 7);
      gload_lds16(ga0 + (size_t)row * EE + kt * 64 + cb * 8, &As[row * 64 + scs * 8]);
      gload_lds16(gb0 + (size_t)row * EE + kt * 64 + cb * 8, &Bs[row * 64 + scs * 8]);
    }
    __syncthreads();
#pragma unroll
    for (int kk = 0; kk < 2; kk++) {
      bf16x8 af[4], bfr[4];
#pragma unroll
      for (int m = 0; m < 4; m++) {
        int row = wr + m * 16 + (l & 15);
        int cc = kk * 4 + (l >> 4);
        int cs = cc ^ (row & 7);
        af[m] = *(const bf16x8*)&As[row * 64 + cs * 8];
      }
#pragma unroll
      for (int n = 0; n < 4; n++) {
        int row = wc + n * 16 + (l & 15);
        int cc = kk * 4 + (l >> 4);
        int cs = cc ^ (row & 7);
        bfr[n] = *(const bf16x8*)&Bs[row * 64 + cs * 8];
      }
#pragma unroll
      for (int m = 0; m < 4; m++)
#pragma unroll
        for (int n = 0; n < 4; n++)
          acc[m][n] = __builtin_amdgcn_mfma_f32_16x16x32_bf16(bfr[n], af[m], acc[m][n], 0, 0, 0);
    }
  }

  float4 bo4[4];
#pragma unroll
  for (int n = 0; n < 4; n++)
    bo4[n] = *(const float4*)(bout + nt * 128 + wc + n * 16 + (l >> 4) * 4);
#pragma unroll
  for (int m = 0; m < 4; m++) {
    float* orow = out + (size_t)(mt * 128 + wr + m * 16 + (l & 15)) * VV
                      + nt * 128 + wc + (l >> 4) * 4;
#pragma unroll
    for (int n = 0; n < 4; n++) {
      float4 v;
      v.x = acc[m][n][0] + bo4[n].x;
      v.y = acc[m][n][1] + bo4[n].y;
      v.z = acc[m][n][2] + bo4[n].z;
      v.w = acc[m][n][3] + bo4[n].w;
      *(float4*)(orow + n * 16) = v;
    }
  }
}

// ---------------------------------------------------------------------------
extern "C" void kernel_launch(void* const* d_in, const int* in_sizes, int n_in,
                              void* d_out, int out_size, void* d_ws, size_t ws_size,
                              hipStream_t stream) {
  const float* feat = (const float*)d_in[0];
  const int* cap = (const int*)d_in[1];
  // d_in[2] = seq_len (constant 32)
  const float* emb = (const float*)d_in[3];
  const float* Wih = (const float*)d_in[4];
  const float* Whh = (const float*)d_in[5];
  const float* bih = (const float*)d_in[6];
  const float* bhh = (const float*)d_in[7];
  const float* Wout = (const float*)d_in[8];
  const float* bout = (const float*)d_in[9];
  float* out = (float*)d_out;

  char* ws = (char*)d_ws;
  float* Gpre = (float*)ws;                                   // 17,301,504
  unsigned short* hall = (unsigned short*)(ws + 17301504);    //  2,097,152 (b-major)
  unsigned short* Wb = (unsigned short*)(ws + 19398656);      // 32,768,000
  unsigned int* hseq = (unsigned int*)(ws + 52166656);        //  4,325,376 (33 steps)
  int* flags = (int*)(ws + 56492032);                         //        256

  k_zero<<<dim3(1), dim3(64), 0, stream>>>(flags);
  k_gemm_ih<<<dim3(17 * 16), dim3(256), 0, stream>>>(feat, cap, emb, Wih, bih, bhh, Gpre);
  k_cast<<<dim3(2048), dim3(256), 0, stream>>>(Wout, Wb, (VV * HH) / 4);
  k_rnn<<<dim3(64), dim3(256), 0, stream>>>(Gpre, Whh, hseq, hall, flags);
  k_gemm_out<<<dim3(4000), dim3(256), 0, stream>>>(hall, Wb, bout, out);
}

// Round 6
// 491.256 us; speedup vs baseline: 1.3665x; 1.1358x over previous
//
#include <hip/hip_runtime.h>
#include <stdint.h>

// Problem dims (fixed)
#define BB 64
#define TT 32
#define EE 512
#define HH 512
#define VV 32000
#define G4 2048

typedef _Float16 f16x8 __attribute__((ext_vector_type(8)));
typedef float f32x4 __attribute__((ext_vector_type(4)));

__device__ __forceinline__ unsigned short f2h(float f) {
  return __builtin_bit_cast(unsigned short, (_Float16)f);   // RNE hw cvt
}
__device__ __forceinline__ void gload_lds16(const unsigned short* g, unsigned short* l) {
  __builtin_amdgcn_global_load_lds((const __attribute__((address_space(1))) void*)g,
                                   (__attribute__((address_space(3))) void*)l, 16, 0, 0);
}
__device__ __forceinline__ float sigm(float x) { return 1.f / (1.f + __expf(-x)); }
__device__ __forceinline__ float tanh_fast(float x) {
  return 1.f - 2.f / (__expf(2.f * x) + 1.f);   // stable at +-inf
}

// ---------------------------------------------------------------------------
// Kernel 1: Gpre(2112 x 2048) = [feat; emb[cap]] @ W_ih.T + (b_ih + b_hh) [fp32]
// ---------------------------------------------------------------------------
__global__ __launch_bounds__(256) void k_gemm_ih(const float* __restrict__ feat,
                                                 const int* __restrict__ cap,
                                                 const float* __restrict__ emb,
                                                 const float* __restrict__ Bw,
                                                 const float* __restrict__ bih,
                                                 const float* __restrict__ bhh,
                                                 float* __restrict__ C) {
  __shared__ float As[16][128];
  __shared__ float Bs[16][128];
  const int tid = threadIdx.x;
  const int bx = blockIdx.x & 15;   // n tile 0..15
  const int by = blockIdx.x >> 4;   // m tile 0..16
  const int m0 = by * 128, n0 = bx * 128;
  const int tx = tid & 15, ty = tid >> 4;

  float acc[8][8];
#pragma unroll
  for (int i = 0; i < 8; i++)
#pragma unroll
    for (int j = 0; j < 8; j++) acc[i][j] = 0.f;

  const int lr = tid >> 1;           // row-in-tile 0..127
  const int lk = (tid & 1) * 8;      // 0 or 8
  int arow = m0 + lr; if (arow > 2111) arow = 2111;  // clamp (store guarded)
  const float* Ap;
  if (arow < BB) {
    Ap = feat + (size_t)arow * EE + lk;
  } else {
    int idx = arow - BB;
    int t = idx >> 6, b = idx & 63;
    Ap = emb + (size_t)cap[b * TT + t] * EE + lk;
  }
  const int brow = n0 + lr;          // < 2048 always
  const float* Bp = Bw + (size_t)brow * EE + lk;

  for (int k0 = 0; k0 < EE; k0 += 16) {
    float4 a0 = *(const float4*)(Ap + k0);
    float4 a1 = *(const float4*)(Ap + k0 + 4);
    float4 b0 = *(const float4*)(Bp + k0);
    float4 b1 = *(const float4*)(Bp + k0 + 4);
    __syncthreads();
    As[lk + 0][lr] = a0.x; As[lk + 1][lr] = a0.y; As[lk + 2][lr] = a0.z; As[lk + 3][lr] = a0.w;
    As[lk + 4][lr] = a1.x; As[lk + 5][lr] = a1.y; As[lk + 6][lr] = a1.z; As[lk + 7][lr] = a1.w;
    Bs[lk + 0][lr] = b0.x; Bs[lk + 1][lr] = b0.y; Bs[lk + 2][lr] = b0.z; Bs[lk + 3][lr] = b0.w;
    Bs[lk + 4][lr] = b1.x; Bs[lk + 5][lr] = b1.y; Bs[lk + 6][lr] = b1.z; Bs[lk + 7][lr] = b1.w;
    __syncthreads();
#pragma unroll
    for (int k = 0; k < 16; k++) {
      float a[8], b[8];
      *(float4*)&a[0] = *(const float4*)&As[k][ty * 8];
      *(float4*)&a[4] = *(const float4*)&As[k][ty * 8 + 4];
      *(float4*)&b[0] = *(const float4*)&Bs[k][tx * 8];
      *(float4*)&b[4] = *(const float4*)&Bs[k][tx * 8 + 4];
#pragma unroll
      for (int i = 0; i < 8; i++)
#pragma unroll
        for (int j = 0; j < 8; j++) acc[i][j] += a[i] * b[j];
    }
  }

  float bs[8];
#pragma unroll
  for (int j = 0; j < 8; j++) {
    int n = n0 + tx * 8 + j;
    bs[j] = bih[n] + bhh[n];
  }
#pragma unroll
  for (int i = 0; i < 8; i++) {
    int m = m0 + ty * 8 + i;
    if (m < 2112) {
      float4 o0, o1;
      o0.x = acc[i][0] + bs[0]; o0.y = acc[i][1] + bs[1];
      o0.z = acc[i][2] + bs[2]; o0.w = acc[i][3] + bs[3];
      o1.x = acc[i][4] + bs[4]; o1.y = acc[i][5] + bs[5];
      o1.z = acc[i][6] + bs[6]; o1.w = acc[i][7] + bs[7];
      *(float4*)(C + (size_t)m * G4 + n0 + tx * 8) = o0;
      *(float4*)(C + (size_t)m * G4 + n0 + tx * 8 + 4) = o1;
    }
  }
}

// ---------------------------------------------------------------------------
// Kernel 2: cast W_out f32 -> fp16 (bits in ushort)
// ---------------------------------------------------------------------------
__global__ void k_cast(const float* __restrict__ src, unsigned short* __restrict__ dst, int n4) {
  int i = blockIdx.x * blockDim.x + threadIdx.x;
  int stride = gridDim.x * blockDim.x;
  for (; i < n4; i += stride) {
    float4 v = ((const float4*)src)[i];
    ushort4 o;
    o.x = f2h(v.x); o.y = f2h(v.y); o.z = f2h(v.z); o.w = f2h(v.w);
    ((ushort4*)dst)[i] = o;
  }
}

// ---------------------------------------------------------------------------
// Kernel 3: zero the barrier flags at the coherence point (agent atomics)
// ---------------------------------------------------------------------------
__global__ void k_zero(int* flags) {
  __hip_atomic_store(&flags[threadIdx.x], 0, __ATOMIC_RELAXED, __HIP_MEMORY_SCOPE_AGENT);
}

// ---------------------------------------------------------------------------
// Fence-free device barrier for 64 co-resident blocks (proven r3-r5).
// h WRITTEN with relaxed agent atomics (coherence point), READ with plain
// cached loads (reader never touches an hseq[s] line before this barrier).
// ---------------------------------------------------------------------------
__device__ __forceinline__ void gridbar_nf(int* flags, int id) {
  asm volatile("s_waitcnt vmcnt(0)" ::: "memory");
  __syncthreads();
  if (threadIdx.x == 0)
    __hip_atomic_store(&flags[blockIdx.x], id, __ATOMIC_RELAXED, __HIP_MEMORY_SCOPE_AGENT);
  if (threadIdx.x < 64) {
    while (__hip_atomic_load(&flags[threadIdx.x], __ATOMIC_RELAXED, __HIP_MEMORY_SCOPE_AGENT) < id)
      __builtin_amdgcn_s_sleep(1);
  }
  __syncthreads();
}

// ---------------------------------------------------------------------------
// Kernel 4: persistent LSTM recurrence, fp16 single-precision-weights.
// 64 blocks x 512 thr (8 waves, 2/SIMD). Block owns u0=bid*8 (8 u x 4 gates
// = 32 W-rows, fp16 in 32KB LDS, 16B-chunk XOR swizzle). Wave (nt=w&1,
// mt=w>>1): 1 n-tile x 1 m-tile, 16 fp16 MFMAs/step, full M=16.
// Gate combine via XOR-swizzled LDS gate_buf (8KB). Epilogue: 1 (s,du)
// update/thread, c in reg, h-pair packed u32 via shfl and atomic-stored to
// hseq (coherence point). Gpre prefetched pre-barrier. hall fp16 b-major.
// ---------------------------------------------------------------------------
__global__ __launch_bounds__(512) void k_rnn(const float* __restrict__ Gpre,
                                             const float* __restrict__ Whh,
                                             char* hseq_base,
                                             unsigned short* __restrict__ hall,
                                             int* __restrict__ flags) {
  __shared__ __align__(16) unsigned short W_lds[32 * 512];  // fp16 bits, 32 KB
  __shared__ float gate_buf[2048];                          // 8 KB
  unsigned short* hseq16 = (unsigned short*)hseq_base;
  unsigned int* hseq32 = (unsigned int*)hseq_base;

  const int tid = threadIdx.x;
  const int bid = blockIdx.x;
  const int u0 = bid * 8;
  const int l = tid & 63;
  const int w = tid >> 6;          // wave 0..7
  const int lr = l & 15;
  const int kc = l >> 4;           // 0..3
  const int nt = w & 1;            // n-tile (W-row half)
  const int mt = w >> 1;           // m-tile (16-sample group)
  // epilogue ownership: one (sample, du) per thread
  const int es = w * 8 + (l >> 3); // 0..63
  const int edu = l & 7;           // 0..7

  // ---- stage W_hh (f32 -> fp16) into LDS, swizzled ----
  {
    int row = tid >> 4;            // 0..31  (= g*8 + du)
    int sub = tid & 15;
    int g = row >> 3, du = row & 7;
    const float* srcp = Whh + (size_t)(g * 512 + u0 + du) * HH;
#pragma unroll
    for (int c0 = 0; c0 < 4; ++c0) {
      int c = sub * 4 + c0;        // 16B-chunk index 0..63 (8 f32 -> 8 fp16)
      float4 va = *(const float4*)(srcp + c * 8);
      float4 vb = *(const float4*)(srcp + c * 8 + 4);
      __align__(16) unsigned short t8[8];
      t8[0] = f2h(va.x); t8[1] = f2h(va.y); t8[2] = f2h(va.z); t8[3] = f2h(va.w);
      t8[4] = f2h(vb.x); t8[5] = f2h(vb.y); t8[6] = f2h(vb.z); t8[7] = f2h(vb.w);
      *(int4*)((char*)W_lds + row * 1024 + ((c ^ (row & 7)) * 16)) = *(const int4*)t8;
    }
  }

  // ---- prime step (h=c=0): elementwise from Gpre rows 0..63 ----
  float c_reg;
  {
    const float* gp = Gpre + (size_t)es * G4 + u0 + edu;
    float gi = gp[0], gg = gp[1024], go = gp[1536];
    float cn = sigm(gi) * tanh_fast(gg);
    float hn = sigm(go) * tanh_fast(cn);
    c_reg = cn;
    unsigned int hb = f2h(hn);
    unsigned int other = (unsigned int)__shfl_xor((int)hb, 1);
    if (!(l & 1))
      __hip_atomic_store(&hseq32[(size_t)es * 256 + bid * 4 + (edu >> 1)],
                         hb | (other << 16), __ATOMIC_RELAXED, __HIP_MEMORY_SCOPE_AGENT);
  }

  // ---- prefetch Gpre gate values for step 1 (drained by barrier vmcnt) ----
  float pre[4];
#pragma unroll
  for (int g = 0; g < 4; ++g)
    pre[g] = Gpre[((size_t)(1 * 64) + es) * G4 + g * 512 + u0 + edu];

  gridbar_nf(flags, 1);   // covers W staging (lds) + h0 stores

  // ---- 32 recurrent steps ----
  for (int s = 1; s <= TT; ++s) {
    const unsigned short* hin = hseq16 + (size_t)(s - 1) * BB * HH;

    // MFMA phase: acc[sample-row][W-row col] over K=512
    f32x4 acc = {0.f, 0.f, 0.f, 0.f};
    const unsigned short* hbase = hin + (size_t)(mt * 16 + lr) * HH + kc * 8;
    const int wrow = nt * 16 + lr;
    const char* wbase = (const char*)W_lds + wrow * 1024;
#pragma unroll
    for (int kk = 0; kk < 16; ++kk) {
      uint4 hq = *(const uint4*)(hbase + kk * 32);
      int4 wq = *(const int4*)(wbase + (((kk * 4 + kc) ^ (wrow & 7)) * 16));
      f16x8 hf = __builtin_bit_cast(f16x8, hq);
      f16x8 wf = __builtin_bit_cast(f16x8, wq);
      acc = __builtin_amdgcn_mfma_f32_16x16x32_f16(hf, wf, acc, 0, 0, 0);
    }

    // write gate partials to LDS (XOR-swizzled on sample index)
    {
      int g = nt * 2 + (lr >> 3);
      int du = lr & 7;
#pragma unroll
      for (int j = 0; j < 4; ++j) {
        int ss = mt * 16 + kc * 4 + j;
        gate_buf[g * 512 + du * 64 + (ss ^ (du << 3))] = acc[j];
      }
    }
    __syncthreads();

    // epilogue: one (es, edu) update per thread
    {
      float gi = gate_buf[0 * 512 + edu * 64 + (es ^ (edu << 3))] + pre[0];
      float gf = gate_buf[1 * 512 + edu * 64 + (es ^ (edu << 3))] + pre[1];
      float gg = gate_buf[2 * 512 + edu * 64 + (es ^ (edu << 3))] + pre[2];
      float go = gate_buf[3 * 512 + edu * 64 + (es ^ (edu << 3))] + pre[3];
      float cn = sigm(gf) * c_reg + sigm(gi) * tanh_fast(gg);
      float hn = sigm(go) * tanh_fast(cn);
      c_reg = cn;
      unsigned int hb = f2h(hn);
      unsigned int other = (unsigned int)__shfl_xor((int)hb, 1);
      if (!(l & 1))
        __hip_atomic_store(&hseq32[(size_t)s * 16384 + es * 256 + bid * 4 + (edu >> 1)],
                           hb | (other << 16), __ATOMIC_RELAXED, __HIP_MEMORY_SCOPE_AGENT);
      hall[((size_t)es * TT + (s - 1)) * HH + u0 + edu] = (unsigned short)hb;
    }

    if (s < TT) {
      // prefetch Gpre for step s+1 (overlaps barrier arrival/poll)
#pragma unroll
      for (int g = 0; g < 4; ++g)
        pre[g] = Gpre[((size_t)(s + 1) * 64 + es) * G4 + g * 512 + u0 + edu];
      gridbar_nf(flags, s + 1);
    }
  }
}

// ---------------------------------------------------------------------------
// Kernel 5: Out(2048 x 32000) = hall @ W_out.T + b_out  [fp16 MFMA, f32 out]
// (structure verified r2-r5; dtype bf16 -> fp16)
// ---------------------------------------------------------------------------
__global__ __launch_bounds__(256) void k_gemm_out(const unsigned short* __restrict__ Xb,
                                                  const unsigned short* __restrict__ Wb,
                                                  const float* __restrict__ bout,
                                                  float* __restrict__ out) {
  __shared__ __align__(16) unsigned short As[128 * 64];
  __shared__ __align__(16) unsigned short Bs[128 * 64];
  const int tid = threadIdx.x;
  int bid = blockIdx.x;
  int swz = (bid & 7) * 500 + (bid >> 3);  // 8 XCDs x 500-block chunks
  const int mt = swz & 15;
  const int nt = swz >> 4;
  const int l = tid & 63;
  const int w = tid >> 6;
  const int wr = (w >> 1) * 64;
  const int wc = (w & 1) * 64;

  const f32x4 vz = {0.f, 0.f, 0.f, 0.f};
  f32x4 acc[4][4];
#pragma unroll
  for (int m = 0; m < 4; m++)
#pragma unroll
    for (int n = 0; n < 4; n++) acc[m][n] = vz;

  const int srow = tid >> 3;
  const int scs = tid & 7;
  const unsigned short* ga0 = Xb + (size_t)(mt * 128) * EE;
  const unsigned short* gb0 = Wb + (size_t)(nt * 128) * EE;

  for (int kt = 0; kt < 8; kt++) {
    if (kt) __syncthreads();
#pragma unroll
    for (int i = 0; i < 4; i++) {
      int row = i * 32 + srow;
      int cb = scs ^ (row & 7);
      gload_lds16(ga0 + (size_t)row * EE + kt * 64 + cb * 8, &As[row * 64 + scs * 8]);
      gload_lds16(gb0 + (size_t)row * EE + kt * 64 + cb * 8, &Bs[row * 64 + scs * 8]);
    }
    __syncthreads();
#pragma unroll
    for (int kk = 0; kk < 2; kk++) {
      f16x8 af[4], bfr[4];
#pragma unroll
      for (int m = 0; m < 4; m++) {
        int row = wr + m * 16 + (l & 15);
        int cc = kk * 4 + (l >> 4);
        int cs = cc ^ (row & 7);
        af[m] = *(const f16x8*)&As[row * 64 + cs * 8];
      }
#pragma unroll
      for (int n = 0; n < 4; n++) {
        int row = wc + n * 16 + (l & 15);
        int cc = kk * 4 + (l >> 4);
        int cs = cc ^ (row & 7);
        bfr[n] = *(const f16x8*)&Bs[row * 64 + cs * 8];
      }
#pragma unroll
      for (int m = 0; m < 4; m++)
#pragma unroll
        for (int n = 0; n < 4; n++)
          acc[m][n] = __builtin_amdgcn_mfma_f32_16x16x32_f16(bfr[n], af[m], acc[m][n], 0, 0, 0);
    }
  }

  float4 bo4[4];
#pragma unroll
  for (int n = 0; n < 4; n++)
    bo4[n] = *(const float4*)(bout + nt * 128 + wc + n * 16 + (l >> 4) * 4);
#pragma unroll
  for (int m = 0; m < 4; m++) {
    float* orow = out + (size_t)(mt * 128 + wr + m * 16 + (l & 15)) * VV
                      + nt * 128 + wc + (l >> 4) * 4;
#pragma unroll
    for (int n = 0; n < 4; n++) {
      float4 v;
      v.x = acc[m][n][0] + bo4[n].x;
      v.y = acc[m][n][1] + bo4[n].y;
      v.z = acc[m][n][2] + bo4[n].z;
      v.w = acc[m][n][3] + bo4[n].w;
      *(float4*)(orow + n * 16) = v;
    }
  }
}

// ---------------------------------------------------------------------------
extern "C" void kernel_launch(void* const* d_in, const int* in_sizes, int n_in,
                              void* d_out, int out_size, void* d_ws, size_t ws_size,
                              hipStream_t stream) {
  const float* feat = (const float*)d_in[0];
  const int* cap = (const int*)d_in[1];
  // d_in[2] = seq_len (constant 32)
  const float* emb = (const float*)d_in[3];
  const float* Wih = (const float*)d_in[4];
  const float* Whh = (const float*)d_in[5];
  const float* bih = (const float*)d_in[6];
  const float* bhh = (const float*)d_in[7];
  const float* Wout = (const float*)d_in[8];
  const float* bout = (const float*)d_in[9];
  float* out = (float*)d_out;

  char* ws = (char*)d_ws;
  float* Gpre = (float*)ws;                                   // 17,301,504
  unsigned short* hall = (unsigned short*)(ws + 17301504);    //  2,097,152 (fp16, b-major)
  unsigned short* Wb = (unsigned short*)(ws + 19398656);      // 32,768,000 (fp16)
  char* hseq = ws + 52166656;                                 //  2,162,688 (33 x 64 x 512 fp16)
  int* flags = (int*)(ws + 54329344);                         //        256

  k_zero<<<dim3(1), dim3(64), 0, stream>>>(flags);
  k_gemm_ih<<<dim3(17 * 16), dim3(256), 0, stream>>>(feat, cap, emb, Wih, bih, bhh, Gpre);
  k_cast<<<dim3(2048), dim3(256), 0, stream>>>(Wout, Wb, (VV * HH) / 4);
  k_rnn<<<dim3(64), dim3(512), 0, stream>>>(Gpre, Whh, hseq, hall, flags);
  k_gemm_out<<<dim3(4000), dim3(256), 0, stream>>>(hall, Wb, bout, out);
}